// Round 1
// baseline (589.357 us; speedup 1.0000x reference)
//
#include <hip/hip_runtime.h>
#include <math.h>

#define N_ENT 64368
#define DIM 128
#define BATCH 512
#define SEQ 50

// ws float layout
#define WS_QW1 0        // 128
#define WS_QW2 128      // 128
#define WS_QS  256      // 1  (soft_bias * sum(q))
#define WS_PE  512      // 50*128 = 6400 -> ends 6912
#define WS_ROWSUM 7168  // 512 -> ends 7680
#define WS_UEMB 8192    // 512*128 -> ends 73728   (~295 KB total)

// ---------------- kernel 0: qW1/qW2/qs, positional-encoding table, zero rowsum
__global__ __launch_bounds__(128) void prep_kernel(
    const float* __restrict__ W1, const float* __restrict__ W2,
    const float* __restrict__ q, const float* __restrict__ soft_bias,
    float* __restrict__ ws) {
  int d = threadIdx.x;  // 0..127
  float s1 = 0.f, s2 = 0.f;
  for (int e = 0; e < DIM; ++e) {
    float qe = q[e];
    s1 += qe * W1[e * DIM + d];
    s2 += qe * W2[e * DIM + d];
  }
  ws[WS_QW1 + d] = s1;
  ws[WS_QW2 + d] = s2;

  __shared__ float red[128];
  red[d] = q[d];
  __syncthreads();
  for (int off = 64; off > 0; off >>= 1) {
    if (d < off) red[d] += red[d + off];
    __syncthreads();
  }
  if (d == 0) ws[WS_QS] = soft_bias[0] * red[0];

  // pe[l, d]: even d -> sin(l*div)/1000, odd d -> cos(l*div)/1000
  int i = d >> 1;
  float div = expf((float)(2 * i) * (-logf(10000.0f) / (float)DIM));
  for (int l = 0; l < SEQ; ++l) {
    float ang = (float)l * div;
    float v = (d & 1) ? cosf(ang) : sinf(ang);
    ws[WS_PE + l * DIM + d] = v * 0.001f;
  }
  // zero rowsum accumulators (ws is poisoned 0xAA every call)
  for (int r = d; r < BATCH; r += 128) ws[WS_ROWSUM + r] = 0.f;
}

// ---------------- kernel 1: per-batch u_emb
__global__ __launch_bounds__(128) void uemb_kernel(
    const float* __restrict__ emb, const int* __restrict__ seeds,
    float* __restrict__ ws) {
  int b = blockIdx.x;
  int d = threadIdx.x;  // 128 threads
  __shared__ float v[SEQ][DIM];
  __shared__ float att[SEQ];
  __shared__ float csh;

  const int* sb = seeds + b * SEQ;
  for (int l = 0; l < SEQ; ++l) {
    int idx = sb[l];
    v[l][d] = emb[idx * DIM + d] + ws[WS_PE + l * DIM + d];
  }
  __syncthreads();

  int wave = d >> 6, lane = d & 63;
  if (wave == 0) {
    float s = ws[WS_QW2 + lane] * v[SEQ - 1][lane] +
              ws[WS_QW2 + 64 + lane] * v[SEQ - 1][64 + lane];
#pragma unroll
    for (int m = 32; m; m >>= 1) s += __shfl_xor(s, m, 64);
    if (lane == 0) csh = s + ws[WS_QS];
  }
  __syncthreads();
  float c = csh;

  for (int l = wave * 25; l < wave * 25 + 25; ++l) {
    float s = ws[WS_QW1 + lane] * v[l][lane] +
              ws[WS_QW1 + 64 + lane] * v[l][64 + lane];
#pragma unroll
    for (int m = 32; m; m >>= 1) s += __shfl_xor(s, m, 64);
    if (lane == 0) att[l] = s + c;
  }
  __syncthreads();

  float u = 0.f;
  for (int l = 0; l < SEQ; ++l) u += att[l] * v[l][d];
  ws[WS_UEMB + b * DIM + d] = u;
}

// ---------------- kernel 2: scores GEMM (M=512,N=64368,K=128) + fused exp-partials
#define BM 64
#define BN 64
#define LDP 132  // padded row stride (floats): 4*132 % 32 = 16 -> max 2-way (free)

__global__ __launch_bounds__(256) void scores_kernel(
    const float* __restrict__ emb, const float* __restrict__ out_bias,
    float* __restrict__ ws, float* __restrict__ out) {
  __shared__ float a_lds[BM * LDP];
  __shared__ float b_lds[BN * LDP];

  int tid = threadIdx.x;
  int tx = tid & 15;        // 0..15
  int ty = tid >> 4;        // 0..15
  int rowBase = blockIdx.y * BM;
  int colBase = blockIdx.x * BN;

  // stage u_emb tile (contiguous 64x128)
  const float* uemb = ws + WS_UEMB + (size_t)rowBase * DIM;
  for (int t = tid; t < BM * DIM / 4; t += 256) {
    int r = t >> 5, c4 = t & 31;  // 32 float4 per row
    float4 vv = reinterpret_cast<const float4*>(uemb)[t];
    *reinterpret_cast<float4*>(&a_lds[r * LDP + c4 * 4]) = vv;
  }
  // stage entity tile (contiguous rows colBase..colBase+63), bounds-checked
  for (int t = tid; t < BN * DIM / 4; t += 256) {
    int r = t >> 5, c4 = t & 31;
    int e = colBase + r;
    float4 vv = (e < N_ENT)
                    ? reinterpret_cast<const float4*>(emb + (size_t)e * DIM)[c4]
                    : make_float4(0.f, 0.f, 0.f, 0.f);
    *reinterpret_cast<float4*>(&b_lds[r * LDP + c4 * 4]) = vv;
  }
  __syncthreads();

  float acc[4][4] = {};
#pragma unroll 4
  for (int k = 0; k < DIM; k += 4) {
    float4 a[4], bb[4];
#pragma unroll
    for (int i = 0; i < 4; ++i)
      a[i] = *reinterpret_cast<const float4*>(&a_lds[(ty + 16 * i) * LDP + k]);
#pragma unroll
    for (int j = 0; j < 4; ++j)
      bb[j] = *reinterpret_cast<const float4*>(&b_lds[(tx + 16 * j) * LDP + k]);
#pragma unroll
    for (int i = 0; i < 4; ++i)
#pragma unroll
      for (int j = 0; j < 4; ++j) {
        acc[i][j] += a[i].x * bb[j].x + a[i].y * bb[j].y +
                     a[i].z * bb[j].z + a[i].w * bb[j].w;
      }
  }

  // epilogue: add bias, store, accumulate per-row sum(exp(score))
#pragma unroll
  for (int i = 0; i < 4; ++i) {
    int row = rowBase + ty + 16 * i;
    float p = 0.f;
#pragma unroll
    for (int j = 0; j < 4; ++j) {
      int col = colBase + tx + 16 * j;
      if (col < N_ENT) {
        float s = acc[i][j] + out_bias[col];
        out[(size_t)row * N_ENT + col] = s;
        p += __expf(s);
      }
    }
    // reduce p across the 16 tx lanes (masks <16 stay within tx group)
#pragma unroll
    for (int m = 8; m; m >>= 1) p += __shfl_xor(p, m, 64);
    if (tx == 0) atomicAdd(&ws[WS_ROWSUM + row], p);
  }
}

// ---------------- kernel 3: loss = mean(log(rowsum) - picked)
__global__ __launch_bounds__(512) void loss_kernel(
    const float* __restrict__ scores, const float* __restrict__ rowsum,
    const int* __restrict__ labels, float* __restrict__ out_loss) {
  __shared__ float red[512];
  int t = threadIdx.x;
  float v = logf(rowsum[t]) - scores[(size_t)t * N_ENT + labels[t]];
  red[t] = v;
  __syncthreads();
  for (int off = 256; off > 0; off >>= 1) {
    if (t < off) red[t] += red[t + off];
    __syncthreads();
  }
  if (t == 0) out_loss[0] = red[0] / (float)BATCH;
}

extern "C" void kernel_launch(void* const* d_in, const int* in_sizes, int n_in,
                              void* d_out, int out_size, void* d_ws, size_t ws_size,
                              hipStream_t stream) {
  const float* entity_emb = (const float*)d_in[0];
  const float* W1 = (const float*)d_in[1];
  const float* W2 = (const float*)d_in[2];
  const float* q = (const float*)d_in[3];
  const float* soft_bias = (const float*)d_in[4];
  const float* out_bias = (const float*)d_in[5];
  const int* seeds = (const int*)d_in[6];
  const int* labels = (const int*)d_in[7];
  float* out = (float*)d_out;
  float* ws = (float*)d_ws;

  prep_kernel<<<1, 128, 0, stream>>>(W1, W2, q, soft_bias, ws);
  uemb_kernel<<<BATCH, 128, 0, stream>>>(entity_emb, seeds, ws);
  dim3 g2((N_ENT + BN - 1) / BN, BATCH / BM);
  scores_kernel<<<g2, 256, 0, stream>>>(entity_emb, out_bias, ws, out);
  loss_kernel<<<1, 512, 0, stream>>>(out, ws + WS_ROWSUM, labels,
                                     out + (size_t)BATCH * N_ENT);
}

// Round 2
// 218.608 us; speedup vs baseline: 2.6959x; 2.6959x over previous
//
#include <hip/hip_runtime.h>
#include <math.h>

#define N_ENT 64368
#define DIM 128
#define BATCH 512
#define SEQ 50

// ws float-index layout (total footprint 256 KB)
#define WS_QW1 0         // 128 floats
#define WS_QW2 128       // 128 floats
#define WS_QS  256       // 1 float (soft_bias * sum(q))
#define WS_PE  512       // 50*128 = 6400 -> ends 6912
#define WS_PART 7168     // 32 slots * 512 rows f32 -> ends 23552 (zeroed via memsetAsync)
#define WS_ABF_BYTES 131072  // bf16 u_emb, 512*128 shorts = 128 KB -> ends byte 262144
#define NPART 32

typedef __attribute__((ext_vector_type(8))) short short8;
typedef __attribute__((ext_vector_type(4))) float f32x4;

static __device__ __forceinline__ short f2bf(float f) {
  union { float f; unsigned u; } v;
  v.f = f;
  unsigned r = v.u + 0x7FFF + ((v.u >> 16) & 1);  // RNE
  return (short)(r >> 16);
}

// ---------------- kernel 0: qW1/qW2/qs + positional-encoding table
__global__ __launch_bounds__(128) void prep_kernel(
    const float* __restrict__ W1, const float* __restrict__ W2,
    const float* __restrict__ q, const float* __restrict__ soft_bias,
    float* __restrict__ ws) {
  int d = threadIdx.x;  // 0..127
  float s1 = 0.f, s2 = 0.f;
  for (int e = 0; e < DIM; ++e) {
    float qe = q[e];
    s1 += qe * W1[e * DIM + d];
    s2 += qe * W2[e * DIM + d];
  }
  ws[WS_QW1 + d] = s1;
  ws[WS_QW2 + d] = s2;

  __shared__ float red[128];
  red[d] = q[d];
  __syncthreads();
  for (int off = 64; off > 0; off >>= 1) {
    if (d < off) red[d] += red[d + off];
    __syncthreads();
  }
  if (d == 0) ws[WS_QS] = soft_bias[0] * red[0];

  int i = d >> 1;
  float div = expf((float)(2 * i) * (-logf(10000.0f) / (float)DIM));
  for (int l = 0; l < SEQ; ++l) {
    float ang = (float)l * div;
    float v = (d & 1) ? cosf(ang) : sinf(ang);
    ws[WS_PE + l * DIM + d] = v * 0.001f;
  }
}

// ---------------- kernel 1: per-batch u_emb -> bf16
__global__ __launch_bounds__(128) void uemb_kernel(
    const float* __restrict__ emb, const int* __restrict__ seeds,
    float* __restrict__ ws, short* __restrict__ abf) {
  int b = blockIdx.x;
  int d = threadIdx.x;  // 128 threads
  __shared__ float v[SEQ][DIM];
  __shared__ float att[SEQ];
  __shared__ float csh;

  const int* sb = seeds + b * SEQ;
  for (int l = 0; l < SEQ; ++l) {
    int idx = sb[l];
    v[l][d] = emb[idx * DIM + d] + ws[WS_PE + l * DIM + d];
  }
  __syncthreads();

  int wave = d >> 6, lane = d & 63;
  if (wave == 0) {
    float s = ws[WS_QW2 + lane] * v[SEQ - 1][lane] +
              ws[WS_QW2 + 64 + lane] * v[SEQ - 1][64 + lane];
#pragma unroll
    for (int m = 32; m; m >>= 1) s += __shfl_xor(s, m, 64);
    if (lane == 0) csh = s + ws[WS_QS];
  }
  __syncthreads();
  float c = csh;

  for (int l = wave * 25; l < wave * 25 + 25; ++l) {
    float s = ws[WS_QW1 + lane] * v[l][lane] +
              ws[WS_QW1 + 64 + lane] * v[l][64 + lane];
#pragma unroll
    for (int m = 32; m; m >>= 1) s += __shfl_xor(s, m, 64);
    if (lane == 0) att[l] = s + c;
  }
  __syncthreads();

  float u = 0.f;
  for (int l = 0; l < SEQ; ++l) u += att[l] * v[l][d];
  abf[b * DIM + d] = f2bf(u);
}

// ---------------- kernel 2: scores via bf16 MFMA, fused exp-partials
// grid: 1006 blocks (64 entity cols each), 256 threads = 4 waves (2 row-halves x 2 col-halves)
__global__ __launch_bounds__(256) void scores_kernel(
    const float* __restrict__ emb, const float* __restrict__ out_bias,
    const short* __restrict__ abf, float* __restrict__ ws_part,
    float* __restrict__ out) {
  __shared__ float rowpart[BATCH][2];

  const int tid = threadIdx.x;
  const int lane = tid & 63;
  const int wid = tid >> 6;   // 0..3
  const int wr = wid >> 1;    // row half of 64-row chunk
  const int wc = wid & 1;     // col half of 64-col tile
  const int lrow = lane & 15;
  const int lgrp = lane >> 4; // 0..3
  const int colBase = blockIdx.x * 64;

  // B fragments (entity tile, f32 -> bf16) once per block: wave covers 32 cols
  short8 bfrag[2][4];
  float biasv[2];
  bool colok[2];
  int cols[2];
#pragma unroll
  for (int cf = 0; cf < 2; ++cf) {
    int col = colBase + wc * 32 + cf * 16 + lrow;
    cols[cf] = col;
    colok[cf] = (col < N_ENT);
    int e = colok[cf] ? col : (N_ENT - 1);
    biasv[cf] = colok[cf] ? out_bias[col] : 0.f;
#pragma unroll
    for (int ki = 0; ki < 4; ++ki) {
      const float4* p =
          reinterpret_cast<const float4*>(emb + (size_t)e * DIM + ki * 32 + lgrp * 8);
      float4 x0 = p[0];
      float4 x1 = p[1];
      short8 f;
      f[0] = f2bf(x0.x); f[1] = f2bf(x0.y); f[2] = f2bf(x0.z); f[3] = f2bf(x0.w);
      f[4] = f2bf(x1.x); f[5] = f2bf(x1.y); f[6] = f2bf(x1.z); f[7] = f2bf(x1.w);
      bfrag[cf][ki] = f;
    }
  }

  for (int c = 0; c < 8; ++c) {
    const int mBase = c * 64 + wr * 32;

    short8 afrag[2][4];
#pragma unroll
    for (int rf = 0; rf < 2; ++rf)
#pragma unroll
      for (int ki = 0; ki < 4; ++ki) {
        int row = mBase + rf * 16 + lrow;
        afrag[rf][ki] =
            *reinterpret_cast<const short8*>(abf + row * DIM + ki * 32 + lgrp * 8);
      }

    f32x4 acc[2][2];
#pragma unroll
    for (int rf = 0; rf < 2; ++rf)
#pragma unroll
      for (int cf = 0; cf < 2; ++cf)
#pragma unroll
        for (int r = 0; r < 4; ++r) acc[rf][cf][r] = 0.f;

#pragma unroll
    for (int ki = 0; ki < 4; ++ki)
#pragma unroll
      for (int rf = 0; rf < 2; ++rf)
#pragma unroll
        for (int cf = 0; cf < 2; ++cf)
          acc[rf][cf] = __builtin_amdgcn_mfma_f32_16x16x32_bf16(
              afrag[rf][ki], bfrag[cf][ki], acc[rf][cf], 0, 0, 0);

    // epilogue: bias + store + exp partials
#pragma unroll
    for (int rf = 0; rf < 2; ++rf) {
      float pr[4] = {0.f, 0.f, 0.f, 0.f};
#pragma unroll
      for (int cf = 0; cf < 2; ++cf) {
        if (colok[cf]) {
#pragma unroll
          for (int r = 0; r < 4; ++r) {
            int row = mBase + rf * 16 + lgrp * 4 + r;
            float s = acc[rf][cf][r] + biasv[cf];
            out[(size_t)row * N_ENT + cols[cf]] = s;
            pr[r] += __expf(s);
          }
        }
      }
      // reduce across the 16 lanes of each lane-group (cols)
#pragma unroll
      for (int r = 0; r < 4; ++r) {
#pragma unroll
        for (int m = 1; m < 16; m <<= 1) pr[r] += __shfl_xor(pr[r], m, 64);
      }
      if (lrow == 0) {
#pragma unroll
        for (int r = 0; r < 4; ++r)
          rowpart[mBase + rf * 16 + lgrp * 4 + r][wc] = pr[r];
      }
    }
  }
  __syncthreads();

  const int slot = blockIdx.x & (NPART - 1);
  for (int r = tid; r < BATCH; r += 256) {
    atomicAdd(&ws_part[slot * BATCH + r], rowpart[r][0] + rowpart[r][1]);
  }
}

// ---------------- kernel 3: logz + loss (single block)
__global__ __launch_bounds__(512) void loss_kernel(
    const float* __restrict__ scores, const float* __restrict__ ws_part,
    const int* __restrict__ labels, float* __restrict__ out_loss) {
  __shared__ float red[512];
  int t = threadIdx.x;  // = batch row
  float s = 0.f;
#pragma unroll
  for (int p = 0; p < NPART; ++p) s += ws_part[p * BATCH + t];
  float v = logf(s) - scores[(size_t)t * N_ENT + labels[t]];
  red[t] = v;
  __syncthreads();
  for (int off = 256; off > 0; off >>= 1) {
    if (t < off) red[t] += red[t + off];
    __syncthreads();
  }
  if (t == 0) out_loss[0] = red[0] / (float)BATCH;
}

extern "C" void kernel_launch(void* const* d_in, const int* in_sizes, int n_in,
                              void* d_out, int out_size, void* d_ws, size_t ws_size,
                              hipStream_t stream) {
  const float* entity_emb = (const float*)d_in[0];
  const float* W1 = (const float*)d_in[1];
  const float* W2 = (const float*)d_in[2];
  const float* q = (const float*)d_in[3];
  const float* soft_bias = (const float*)d_in[4];
  const float* out_bias = (const float*)d_in[5];
  const int* seeds = (const int*)d_in[6];
  const int* labels = (const int*)d_in[7];
  float* out = (float*)d_out;
  float* ws = (float*)d_ws;
  short* abf = (short*)((char*)d_ws + WS_ABF_BYTES);
  float* ws_part = ws + WS_PART;

  prep_kernel<<<1, 128, 0, stream>>>(W1, W2, q, soft_bias, ws);
  uemb_kernel<<<BATCH, 128, 0, stream>>>(entity_emb, seeds, ws, abf);
  hipMemsetAsync(ws_part, 0, NPART * BATCH * sizeof(float), stream);
  scores_kernel<<<(N_ENT + 63) / 64, 256, 0, stream>>>(entity_emb, out_bias, abf,
                                                       ws_part, out);
  loss_kernel<<<1, 512, 0, stream>>>(out, ws_part, labels,
                                     out + (size_t)BATCH * N_ENT);
}

// Round 3
// 204.744 us; speedup vs baseline: 2.8785x; 1.0677x over previous
//
#include <hip/hip_runtime.h>
#include <math.h>

#define N_ENT 64368
#define DIM 128
#define BATCH 512
#define SEQ 50

// ws float-index layout
#define WS_QW1 0         // 128 floats
#define WS_QW2 128       // 128 floats
#define WS_QS  256       // 1 float (soft_bias * sum(q))
#define WS_PE  512       // 50*128 = 6400 -> ends 6912
#define WS_PART 7168     // 32 slots * 512 rows f32 -> ends 23552 (zeroed in prep)
#define WS_ABF_BYTES 131072  // bf16 u_emb, 512*128 shorts = 128 KB
#define NPART 32

typedef __attribute__((ext_vector_type(8))) short short8;
typedef __attribute__((ext_vector_type(4))) float f32x4;

static __device__ __forceinline__ short f2bf(float f) {
  union { float f; unsigned u; } v;
  v.f = f;
  unsigned r = v.u + 0x7FFF + ((v.u >> 16) & 1);  // RNE
  return (short)(r >> 16);
}

// ---------------- kernel 0: qW1/qW2/qs + PE table + zero ws_part (512 thr)
__global__ __launch_bounds__(512) void prep_kernel(
    const float* __restrict__ W1, const float* __restrict__ W2,
    const float* __restrict__ q, const float* __restrict__ soft_bias,
    float* __restrict__ ws) {
  const int tid = threadIdx.x;
  const int d = tid & 127;
  const int quarter = tid >> 7;  // 0..3

  __shared__ float red1[4][128];
  __shared__ float red2[4][128];
  __shared__ float qsh[128];

  float s1 = 0.f, s2 = 0.f;
  for (int e = quarter * 32; e < quarter * 32 + 32; ++e) {
    float qe = q[e];
    s1 += qe * W1[e * DIM + d];
    s2 += qe * W2[e * DIM + d];
  }
  red1[quarter][d] = s1;
  red2[quarter][d] = s2;
  if (tid < 128) qsh[tid] = q[tid];
  __syncthreads();

  if (tid < 128) {
    ws[WS_QW1 + tid] = red1[0][tid] + red1[1][tid] + red1[2][tid] + red1[3][tid];
    ws[WS_QW2 + tid] = red2[0][tid] + red2[1][tid] + red2[2][tid] + red2[3][tid];
  }
  if (tid == 0) {
    float s = 0.f;
    for (int i = 0; i < 128; ++i) s += qsh[i];
    ws[WS_QS] = soft_bias[0] * s;
  }

  // PE table, spread across all 512 threads
  for (int i = tid; i < SEQ * DIM; i += 512) {
    int l = i >> 7, dd = i & 127;
    float div = expf((float)(dd & ~1) * (-logf(10000.0f) / (float)DIM));
    float ang = (float)l * div;
    float v = (dd & 1) ? cosf(ang) : sinf(ang);
    ws[WS_PE + i] = v * 0.001f;
  }
  // zero the rowsum partial slots (ws is poisoned 0xAA each call)
  for (int i = tid; i < NPART * BATCH; i += 512) ws[WS_PART + i] = 0.f;
}

// ---------------- kernel 1: per-batch u_emb -> bf16 (256 thr, float4 staged)
__global__ __launch_bounds__(256) void uemb_kernel(
    const float* __restrict__ emb, const int* __restrict__ seeds,
    const float* __restrict__ ws, short* __restrict__ abf) {
  const int b = blockIdx.x;
  const int tid = threadIdx.x;
  __shared__ float v[SEQ][DIM];
  __shared__ float att[SEQ];
  __shared__ int sidx[SEQ];
  __shared__ float usum[2][DIM];

  if (tid < SEQ) sidx[tid] = seeds[b * SEQ + tid];
  __syncthreads();

  // stage v = emb[seed] + pe, float4-vectorized: 50*32 float4s
  for (int i = tid; i < SEQ * (DIM / 4); i += 256) {
    int l = i >> 5, c4 = i & 31;
    float4 e4 = reinterpret_cast<const float4*>(emb + (size_t)sidx[l] * DIM)[c4];
    float4 p4 = reinterpret_cast<const float4*>(ws + WS_PE + l * DIM)[c4];
    e4.x += p4.x; e4.y += p4.y; e4.z += p4.z; e4.w += p4.w;
    *reinterpret_cast<float4*>(&v[l][c4 * 4]) = e4;
  }
  __syncthreads();

  const int wave = tid >> 6, lane = tid & 63;
  const float qw1a = ws[WS_QW1 + lane], qw1b = ws[WS_QW1 + 64 + lane];
  const float qw2a = ws[WS_QW2 + lane], qw2b = ws[WS_QW2 + 64 + lane];

  // each wave computes c redundantly (no extra sync)
  float cs = qw2a * v[SEQ - 1][lane] + qw2b * v[SEQ - 1][64 + lane];
#pragma unroll
  for (int m = 32; m; m >>= 1) cs += __shfl_xor(cs, m, 64);
  float c = cs + ws[WS_QS];

  for (int l = wave; l < SEQ; l += 4) {
    float s = qw1a * v[l][lane] + qw1b * v[l][64 + lane];
#pragma unroll
    for (int m = 32; m; m >>= 1) s += __shfl_xor(s, m, 64);
    if (lane == 0) att[l] = s + c;
  }
  __syncthreads();

  // u[d] = sum_l att[l] * v[l][d], split across 2 halves of L
  const int d = tid & 127, h = tid >> 7;
  float u = 0.f;
  for (int l = h * 25; l < h * 25 + 25; ++l) u += att[l] * v[l][d];
  usum[h][d] = u;
  __syncthreads();
  if (tid < 128) abf[b * DIM + tid] = f2bf(usum[0][tid] + usum[1][tid]);
}

// ---------------- kernel 2: scores via bf16 MFMA, fused exp-partials
__global__ __launch_bounds__(256) void scores_kernel(
    const float* __restrict__ emb, const float* __restrict__ out_bias,
    const short* __restrict__ abf, float* __restrict__ ws_part,
    float* __restrict__ out) {
  __shared__ float rowpart[BATCH][2];

  const int tid = threadIdx.x;
  const int lane = tid & 63;
  const int wid = tid >> 6;   // 0..3
  const int wr = wid >> 1;    // row half of 64-row chunk
  const int wc = wid & 1;     // col half of 64-col tile
  const int lrow = lane & 15;
  const int lgrp = lane >> 4; // 0..3
  const int colBase = blockIdx.x * 64;

  short8 bfrag[2][4];
  float biasv[2];
  bool colok[2];
  int cols[2];
#pragma unroll
  for (int cf = 0; cf < 2; ++cf) {
    int col = colBase + wc * 32 + cf * 16 + lrow;
    cols[cf] = col;
    colok[cf] = (col < N_ENT);
    int e = colok[cf] ? col : (N_ENT - 1);
    biasv[cf] = colok[cf] ? out_bias[col] : 0.f;
#pragma unroll
    for (int ki = 0; ki < 4; ++ki) {
      const float4* p =
          reinterpret_cast<const float4*>(emb + (size_t)e * DIM + ki * 32 + lgrp * 8);
      float4 x0 = p[0];
      float4 x1 = p[1];
      short8 f;
      f[0] = f2bf(x0.x); f[1] = f2bf(x0.y); f[2] = f2bf(x0.z); f[3] = f2bf(x0.w);
      f[4] = f2bf(x1.x); f[5] = f2bf(x1.y); f[6] = f2bf(x1.z); f[7] = f2bf(x1.w);
      bfrag[cf][ki] = f;
    }
  }

  for (int c = 0; c < 8; ++c) {
    const int mBase = c * 64 + wr * 32;

    short8 afrag[2][4];
#pragma unroll
    for (int rf = 0; rf < 2; ++rf)
#pragma unroll
      for (int ki = 0; ki < 4; ++ki) {
        int row = mBase + rf * 16 + lrow;
        afrag[rf][ki] =
            *reinterpret_cast<const short8*>(abf + row * DIM + ki * 32 + lgrp * 8);
      }

    f32x4 acc[2][2];
#pragma unroll
    for (int rf = 0; rf < 2; ++rf)
#pragma unroll
      for (int cf = 0; cf < 2; ++cf)
#pragma unroll
        for (int r = 0; r < 4; ++r) acc[rf][cf][r] = 0.f;

#pragma unroll
    for (int ki = 0; ki < 4; ++ki)
#pragma unroll
      for (int rf = 0; rf < 2; ++rf)
#pragma unroll
        for (int cf = 0; cf < 2; ++cf)
          acc[rf][cf] = __builtin_amdgcn_mfma_f32_16x16x32_bf16(
              afrag[rf][ki], bfrag[cf][ki], acc[rf][cf], 0, 0, 0);

#pragma unroll
    for (int rf = 0; rf < 2; ++rf) {
      float pr[4] = {0.f, 0.f, 0.f, 0.f};
#pragma unroll
      for (int cf = 0; cf < 2; ++cf) {
        if (colok[cf]) {
#pragma unroll
          for (int r = 0; r < 4; ++r) {
            int row = mBase + rf * 16 + lgrp * 4 + r;
            float s = acc[rf][cf][r] + biasv[cf];
            out[(size_t)row * N_ENT + cols[cf]] = s;
            pr[r] += __expf(s);
          }
        }
      }
#pragma unroll
      for (int r = 0; r < 4; ++r) {
#pragma unroll
        for (int m = 1; m < 16; m <<= 1) pr[r] += __shfl_xor(pr[r], m, 64);
      }
      if (lrow == 0) {
#pragma unroll
        for (int r = 0; r < 4; ++r)
          rowpart[mBase + rf * 16 + lgrp * 4 + r][wc] = pr[r];
      }
    }
  }
  __syncthreads();

  const int slot = blockIdx.x & (NPART - 1);
  for (int r = tid; r < BATCH; r += 256) {
    atomicAdd(&ws_part[slot * BATCH + r], rowpart[r][0] + rowpart[r][1]);
  }
}

// ---------------- kernel 3: logz + loss (single block)
__global__ __launch_bounds__(512) void loss_kernel(
    const float* __restrict__ scores, const float* __restrict__ ws_part,
    const int* __restrict__ labels, float* __restrict__ out_loss) {
  __shared__ float red[512];
  int t = threadIdx.x;  // = batch row
  float s = 0.f;
#pragma unroll
  for (int p = 0; p < NPART; ++p) s += ws_part[p * BATCH + t];
  float v = logf(s) - scores[(size_t)t * N_ENT + labels[t]];
  red[t] = v;
  __syncthreads();
  for (int off = 256; off > 0; off >>= 1) {
    if (t < off) red[t] += red[t + off];
    __syncthreads();
  }
  if (t == 0) out_loss[0] = red[0] / (float)BATCH;
}

extern "C" void kernel_launch(void* const* d_in, const int* in_sizes, int n_in,
                              void* d_out, int out_size, void* d_ws, size_t ws_size,
                              hipStream_t stream) {
  const float* entity_emb = (const float*)d_in[0];
  const float* W1 = (const float*)d_in[1];
  const float* W2 = (const float*)d_in[2];
  const float* q = (const float*)d_in[3];
  const float* soft_bias = (const float*)d_in[4];
  const float* out_bias = (const float*)d_in[5];
  const int* seeds = (const int*)d_in[6];
  const int* labels = (const int*)d_in[7];
  float* out = (float*)d_out;
  float* ws = (float*)d_ws;
  short* abf = (short*)((char*)d_ws + WS_ABF_BYTES);
  float* ws_part = ws + WS_PART;

  prep_kernel<<<1, 512, 0, stream>>>(W1, W2, q, soft_bias, ws);
  uemb_kernel<<<BATCH, 256, 0, stream>>>(entity_emb, seeds, ws, abf);
  scores_kernel<<<(N_ENT + 63) / 64, 256, 0, stream>>>(entity_emb, out_bias, abf,
                                                       ws_part, out);
  loss_kernel<<<1, 512, 0, stream>>>(out, ws_part, labels,
                                     out + (size_t)BATCH * N_ENT);
}